// Round 6
// baseline (334.970 us; speedup 1.0000x reference)
//
#include <hip/hip_runtime.h>
#include <stdint.h>

// out[f, i] = dot(kernel[f], x[i]) + dot(enc[i % P], x[i])
// x: [372000, 125] f32 (row = 500 B), enc: [23250, 125] f32, w: [125, 64] f32,
// out flat: [64, 372000] f32 (reference reshape is a pure reinterpret).
//
// Round 6: DMA-pipelined persistent-ish blocks. Block = one 32-row p-tile,
// loops over all 16 n. enc tile staged ONCE per block via global_load_lds
// (enc L2 traffic 186 MB -> 12 MB); x tiles are contiguous 16 KB spans,
// double-buffered via global_load_lds with counted vmcnt(2) across raw
// barriers (T3/T4-minimum) so the next tile streams in during compute.

#define P_    23250
#define K_    125
#define F_    64
#define NN    16
#define M_TOT 372000
#define BM    32
#define NPT   727                        // ceil(P/32); last tile has 18 rows
#define TILEB 16384                      // staged envelope bytes per tile
#define XBYTES ((size_t)M_TOT * 500)     // 186,000,000
#define EBYTES ((size_t)P_ * 500)        // 11,625,000

typedef __bf16 bf16;
typedef __bf16 bf16x8 __attribute__((ext_vector_type(8)));
typedef float  f32x4  __attribute__((ext_vector_type(4)));
typedef float  f32x4u __attribute__((ext_vector_type(4), aligned(4)));

// ---- prep: per-(lane,wave) kernel fragments, thread-linear in d_ws ---------
__global__ __launch_bounds__(256, 1)
void prep_wfrag(const float* __restrict__ w, bf16* __restrict__ wfrag)
{
    const int tid = threadIdx.x;
    const int f  = ((tid >> 6) << 4) | (tid & 15);
    const int kg = (tid >> 4) & 3;
    #pragma unroll
    for (int ks = 0; ks < 4; ++ks) {
        bf16x8 fr;
        #pragma unroll
        for (int j = 0; j < 8; ++j) {
            const int k = ks * 32 + kg * 8 + j;
            fr[j] = (bf16)((k < K_) ? w[k * F_ + f] : 0.0f);
        }
        *(bf16x8*)(wfrag + tid * 32 + ks * 8) = fr;
    }
}

// DMA one 16 KB envelope into LDS: 4 rounds x 256 threads x 16 B, per-lane
// source clamped to the buffer end (finite data everywhere, no faults).
#define STAGE16K(GBASE, GLIM, LDSB)                                            \
    do {                                                                       \
        _Pragma("unroll")                                                      \
        for (int r_ = 0; r_ < 4; ++r_) {                                       \
            const char* g_ = (GBASE) + r_ * 4096 + tid * 16;                   \
            if (g_ > (GLIM)) g_ = (GLIM);                                      \
            __builtin_amdgcn_global_load_lds(                                  \
                (const __attribute__((address_space(1))) uint32_t*)g_,         \
                (__attribute__((address_space(3))) uint32_t*)((LDSB) + r_ * 4096 + wvoff), \
                16, 0, 0);                                                     \
        }                                                                      \
    } while (0)

__global__ __launch_bounds__(256, 3)
void eegconv_kernel(const float* __restrict__ x,
                    const float* __restrict__ enc,
                    const bf16* __restrict__ wfrag,
                    float* __restrict__ out)
{
    __shared__ __attribute__((aligned(16))) char encT[TILEB];
    __shared__ __attribute__((aligned(16))) char xT[2][TILEB];
    __shared__ __attribute__((aligned(16))) float srow[BM];

    const int tid  = threadIdx.x;
    const int lane = tid & 63;
    const int wv   = tid >> 6;           // wave -> f-tile [16wv, 16wv+16)
    const int fl   = lane & 15;
    const int kg   = lane >> 4;          // 0..3
    const int wvoff = wv << 10;          // wave-uniform LDS sub-offset

    const int ptile = blockIdx.x;
    const int p0    = ptile * BM;

    // kernel fragments (thread-linear, L2-hot)
    bf16x8 kf[4];
    {
        const bf16x8* wfp = (const bf16x8*)(wfrag + tid * 32);
        #pragma unroll
        for (int ks = 0; ks < 4; ++ks) kf[ks] = wfp[ks];
    }

    const char* xg   = (const char*)x;
    const char* eg   = (const char*)enc;
    const char* xlim = xg + (XBYTES - 16);                    // 16-aligned
    const char* elim = eg + ((EBYTES - 16) & ~(size_t)15);

    // ---- prologue: stage enc tile (persists all 16 n) + x(n=0) ----
    {
        const char* eb = eg + (size_t)p0 * 500;               // 16-aligned
        STAGE16K(eb, elim, encT);
        const size_t xb0 = (size_t)p0 * 500;                  // n=0, 16-aligned
        const char* ab = xg + (xb0 & ~(size_t)15);
        STAGE16K(ab, xlim, xT[0]);
        asm volatile("s_waitcnt vmcnt(0)" ::: "memory");
        __builtin_amdgcn_s_barrier();
        __builtin_amdgcn_sched_barrier(0);
    }

    const size_t xstride = (size_t)P_ * 500;                  // 11,625,000 B
    float* const outb = out + (size_t)(wv * 16 + fl) * M_TOT + p0;
    const bool fullt = (p0 + BM <= P_);                       // 726/727 tiles

    for (int n = 0; n < NN; ++n) {
        const int cur  = n & 1;
        const int xoff = (n & 1) << 3;   // x tile byte base mod 16 = 8*(n&1)

        // ---- issue next tile's DMA (stays in flight across compute) ----
        if (n + 1 < NN) {
            const size_t xb = (size_t)(n + 1) * xstride + (size_t)p0 * 500;
            const char* ab = xg + (xb & ~(size_t)15);
            STAGE16K(ab, xlim, xT[cur ^ 1]);
        }

        // ---- phase A: srow = dot(enc_row, x_row), fp32, 8 lanes/row ----
        {
            const int row = tid >> 3, t8 = tid & 7;
            const float* xr = (const float*)(xT[cur] + xoff + row * 500);
            const float* er = (const float*)(encT + row * 500);
            float part = 0.f;
            #pragma unroll
            for (int u = 0; u < 4; ++u) {
                const int c = u * 8 + t8;        // 0..31
                const int b = c * 4;
                float x0 = xr[b], x1 = xr[b+1], x2 = xr[b+2], x3 = xr[b+3];
                const float e0 = er[b], e1 = er[b+1], e2 = er[b+2], e3 = er[b+3];
                if (c == 31) { x1 = 0.f; x2 = 0.f; x3 = 0.f; }  // cols 125..127
                part += e0*x0 + e1*x1 + e2*x2 + e3*x3;
            }
            part += __shfl_xor(part, 1);
            part += __shfl_xor(part, 2);
            part += __shfl_xor(part, 4);
            if (t8 == 0) srow[row] = part;
        }
        asm volatile("s_waitcnt lgkmcnt(0)" ::: "memory");   // srow visible
        __builtin_amdgcn_s_barrier();                        // vmcnt NOT drained
        __builtin_amdgcn_sched_barrier(0);

        // ---- phase B: fragments (f32->bf16) + MFMA D[i][f] ----
        f32x4 acc0 = {0.f,0.f,0.f,0.f}, acc1 = {0.f,0.f,0.f,0.f};
        #pragma unroll
        for (int t = 0; t < 2; ++t) {
            const int il = t * 16 + fl;
            const float* xrow = (const float*)(xT[cur] + xoff + il * 500);
            #pragma unroll
            for (int ks = 0; ks < 4; ++ks) {
                const int kb = ks * 32 + kg * 8;
                bf16x8 af;
                #pragma unroll
                for (int j = 0; j < 8; ++j) af[j] = (bf16)xrow[kb + j];
                // k>=125 garbage is finite; kf zero-padded there -> product 0
                if (t == 0) acc0 = __builtin_amdgcn_mfma_f32_16x16x32_bf16(af, kf[ks], acc0, 0, 0, 0);
                else        acc1 = __builtin_amdgcn_mfma_f32_16x16x32_bf16(af, kf[ks], acc1, 0, 0, 0);
            }
        }

        // ---- phase C: stores (4 consecutive i per lane) ----
        {
            float* ob = outb + (size_t)n * P_;
            #pragma unroll
            for (int t = 0; t < 2; ++t) {
                const int i0 = t * 16 + kg * 4;
                const f32x4 sv = *(const f32x4*)&srow[i0];
                const f32x4 a = t ? acc1 : acc0;
                f32x4 v;
                v.x = a.x + sv.x; v.y = a.y + sv.y;
                v.z = a.z + sv.z; v.w = a.w + sv.w;
                if (fullt) {
                    *(f32x4u*)(ob + i0) = v;
                } else {
                    #pragma unroll
                    for (int e = 0; e < 4; ++e)
                        if (p0 + i0 + e < P_) ob[i0 + e] = v[e];
                }
            }
        }

        // all waves done reading xT[cur]/srow -> safe for next overwrite;
        // then wait the in-flight DMA (4 loads) with stores (2) still pending.
        __builtin_amdgcn_s_barrier();
        asm volatile("s_waitcnt vmcnt(2)" ::: "memory");
        __builtin_amdgcn_sched_barrier(0);
    }
}

extern "C" void kernel_launch(void* const* d_in, const int* in_sizes, int n_in,
                              void* d_out, int out_size, void* d_ws, size_t ws_size,
                              hipStream_t stream)
{
    const float* x   = (const float*)d_in[0];
    const float* enc = (const float*)d_in[1];
    const float* w   = (const float*)d_in[2];
    float* out = (float*)d_out;
    bf16* wfrag = (bf16*)d_ws;                 // 16 KB
    prep_wfrag<<<1, 256, 0, stream>>>(w, wfrag);
    eegconv_kernel<<<NPT, 256, 0, stream>>>(x, enc, wfrag, out);
}

// Round 9
// 325.547 us; speedup vs baseline: 1.0289x; 1.0289x over previous
//
#include <hip/hip_runtime.h>
#include <stdint.h>

// out[f, i] = dot(kernel[f], x[i]) + dot(enc[i % P], x[i])
// x: [372000, 125] f32, enc: [23250, 125] f32, w: [125, 64] f32,
// out flat: [64, 372000] f32 (reference reshape is a pure reinterpret).
//
// Round 7 (second resubmit — rounds 7 and 8 both hit broker-capacity
// timeouts; this kernel has never been measured):
// barrier-free 1-wave jobs, maximal memory-level parallelism.
// Lane (fl,kg) loads x/enc in the MFMA fragment partition directly:
// x[row t*16+fl][ks*32+kg*8 .. +8]. The enc.x dot is computed in-register
// (kg-reduce via 2 shuffles), the same x regs become MFMA A-fragments.
// 32 f32x4 loads issue back-to-back per lane -> 32 KB in flight per wave,
// ~12 independent waves/CU, no __syncthreads, no x-LDS, no DMA.

#define P_    23250
#define K_    125
#define F_    64
#define M_TOT 372000
#define NPT   727              // ceil(P/32); last tile has 18 valid rows
#define NWG   (NPT * 16)       // 11632 = 8 * 1454 (bijective XCD chunking)
#define CPX   (NWG / 8)

typedef __bf16 bf16;
typedef __bf16 bf16x8 __attribute__((ext_vector_type(8)));
typedef float  f32x4  __attribute__((ext_vector_type(4)));
typedef float  f32x4u __attribute__((ext_vector_type(4), aligned(4)));

// ---- prep: kernel fragments, layout [ftile][lane][ks] -> bf16x8 ------------
// wfrag[ftile*2048 + lane*32 + ks*8 + j] = bf16(w[(ks*32+kg*8+j)*64 + ftile*16+fl])
// (identical indexing to prior rounds with tid = ftile*64+lane)
__global__ __launch_bounds__(256, 1)
void prep_wfrag(const float* __restrict__ w, bf16* __restrict__ wfrag)
{
    const int tid = threadIdx.x;
    const int f  = ((tid >> 6) << 4) | (tid & 15);
    const int kg = (tid >> 4) & 3;
    #pragma unroll
    for (int ks = 0; ks < 4; ++ks) {
        bf16x8 fr;
        #pragma unroll
        for (int j = 0; j < 8; ++j) {
            const int k = ks * 32 + kg * 8 + j;
            fr[j] = (bf16)((k < K_) ? w[k * F_ + f] : 0.0f);
        }
        *(bf16x8*)(wfrag + tid * 32 + ks * 8) = fr;
    }
}

__global__ __launch_bounds__(64, 3)
void eegconv_kernel(const float* __restrict__ x,
                    const float* __restrict__ enc,
                    const bf16* __restrict__ wfrag,
                    float* __restrict__ out)
{
    __shared__ __attribute__((aligned(16))) float srow[32];

    const int lane = threadIdx.x;        // one wave per block
    const int fl   = lane & 15;
    const int kg   = lane >> 4;          // 0..3

    // XCD-chunked bijective swizzle: the 16 n-blocks sharing an enc tile
    // are adjacent within one XCD's contiguous chunk (enc L2-hot).
    const int wgid  = ((int)blockIdx.x & 7) * CPX + ((int)blockIdx.x >> 3);
    const int ptile = wgid >> 4;
    const int n     = wgid & 15;
    const int p0    = ptile * 32;

    // two rows per lane-column (t = 0,1); tail rows clamped (stores guarded)
    const int pa = p0 + fl;        const int pe0 = (pa < P_) ? pa : P_ - 1;
    const int pb = p0 + 16 + fl;   const int pe1 = (pb < P_) ? pb : P_ - 1;

    const float* xr[2] = { x + (size_t)(n * P_ + pe0) * K_,
                           x + (size_t)(n * P_ + pe1) * K_ };
    const float* er[2] = { enc + (size_t)pe0 * K_,
                           enc + (size_t)pe1 * K_ };

    // ---- one straight-line batch of 32 vector loads (32 KB/wave in flight) --
    f32x4 xv[2][4][2], ev[2][4][2];
    #pragma unroll
    for (int t = 0; t < 2; ++t) {
        #pragma unroll
        for (int ks = 0; ks < 4; ++ks) {
            const int b = ks * 32 + kg * 8;
            xv[t][ks][0] = (f32x4)*(const f32x4u*)(xr[t] + b);
            ev[t][ks][0] = (f32x4)*(const f32x4u*)(er[t] + b);
            if (ks == 3 && kg == 3) {   // k = 124 valid; 125..127 structural zeros
                xv[t][ks][1] = f32x4{xr[t][124], 0.f, 0.f, 0.f};
                ev[t][ks][1] = f32x4{er[t][124], 0.f, 0.f, 0.f};
            } else {
                xv[t][ks][1] = (f32x4)*(const f32x4u*)(xr[t] + b + 4);
                ev[t][ks][1] = (f32x4)*(const f32x4u*)(er[t] + b + 4);
            }
        }
    }

    // ---- enc.x dot in-register; reduce over the 4 kg lane-groups ----
    float part[2];
    #pragma unroll
    for (int t = 0; t < 2; ++t) {
        float s = 0.f;
        #pragma unroll
        for (int ks = 0; ks < 4; ++ks)
            #pragma unroll
            for (int u = 0; u < 2; ++u)
                s += ev[t][ks][u].x * xv[t][ks][u].x
                   + ev[t][ks][u].y * xv[t][ks][u].y
                   + ev[t][ks][u].z * xv[t][ks][u].z
                   + ev[t][ks][u].w * xv[t][ks][u].w;
        s += __shfl_xor(s, 16);
        s += __shfl_xor(s, 32);
        part[t] = s;
    }

    // ---- kf loads (L1-hot 8 KB, every wave reads the same) ----
    bf16x8 kf[4][4];
    #pragma unroll
    for (int ft = 0; ft < 4; ++ft)
        #pragma unroll
        for (int ks = 0; ks < 4; ++ks)
            kf[ft][ks] = *(const bf16x8*)(wfrag + ft * 2048 + lane * 32 + ks * 8);

    // ---- fragments: same regs, cvt to bf16 ----
    bf16x8 af[2][4];
    #pragma unroll
    for (int t = 0; t < 2; ++t)
        #pragma unroll
        for (int ks = 0; ks < 4; ++ks) {
            #pragma unroll
            for (int j = 0; j < 4; ++j) {
                af[t][ks][j]     = (bf16)xv[t][ks][0][j];
                af[t][ks][4 + j] = (bf16)xv[t][ks][1][j];
            }
        }

    // ---- srow exchange (tiny LDS, same wave -> no barrier) ----
    if (kg == 0) { srow[fl] = part[0]; srow[16 + fl] = part[1]; }
    asm volatile("s_waitcnt lgkmcnt(0)" ::: "memory");
    f32x4 sv[2];
    #pragma unroll
    for (int t = 0; t < 2; ++t)
        sv[t] = *(const f32x4*)&srow[t * 16 + kg * 4];

    // ---- 32 MFMA: D[i(16 per t)][f(16 per ft)] ----
    f32x4 acc[2][4];
    #pragma unroll
    for (int t = 0; t < 2; ++t)
        #pragma unroll
        for (int ft = 0; ft < 4; ++ft)
            acc[t][ft] = f32x4{0.f, 0.f, 0.f, 0.f};
    #pragma unroll
    for (int ks = 0; ks < 4; ++ks)
        #pragma unroll
        for (int t = 0; t < 2; ++t)
            #pragma unroll
            for (int ft = 0; ft < 4; ++ft)
                acc[t][ft] = __builtin_amdgcn_mfma_f32_16x16x32_bf16(
                    af[t][ks], kf[ft][ks], acc[t][ft], 0, 0, 0);

    // ---- stores: per (ft,t), 16 f-rows x 64 B contiguous per instr ----
    const bool fullt = (p0 + 32 <= P_);
    #pragma unroll
    for (int ft = 0; ft < 4; ++ft) {
        #pragma unroll
        for (int t = 0; t < 2; ++t) {
            const int ip = p0 + t * 16 + kg * 4;          // p-space index
            float* ob = out + (size_t)(ft * 16 + fl) * M_TOT
                            + (size_t)n * P_ + ip;
            f32x4 v;
            v.x = acc[t][ft].x + sv[t].x;
            v.y = acc[t][ft].y + sv[t].y;
            v.z = acc[t][ft].z + sv[t].z;
            v.w = acc[t][ft].w + sv[t].w;
            if (fullt) {
                *(f32x4u*)ob = v;
            } else {
                #pragma unroll
                for (int e = 0; e < 4; ++e)
                    if (ip + e < P_) ob[e] = v[e];
            }
        }
    }
}

extern "C" void kernel_launch(void* const* d_in, const int* in_sizes, int n_in,
                              void* d_out, int out_size, void* d_ws, size_t ws_size,
                              hipStream_t stream)
{
    const float* x   = (const float*)d_in[0];
    const float* enc = (const float*)d_in[1];
    const float* w   = (const float*)d_in[2];
    float* out = (float*)d_out;
    bf16* wfrag = (bf16*)d_ws;                 // 16 KB
    prep_wfrag<<<1, 256, 0, stream>>>(w, wfrag);
    eegconv_kernel<<<NWG, 64, 0, stream>>>(x, enc, wfrag, out);
}